// Round 1
// baseline (80.282 us; speedup 1.0000x reference)
//
#include <hip/hip_runtime.h>

#define NPTS 4096
#define DDIM 256
#define R2 0.015625f
#define MAXDEG 512

// Pre-transpose weights: Wt[j][k] = W1[k][j] - W1[k][j+256]; Vt[j][k] = W1[k][j+256];
// Ct[j][k] = W2[k][j] - W2[k][j+256]  (this is C in the reference).
__global__ void prep_kernel(const float* __restrict__ W1, const float* __restrict__ W2,
                            float* __restrict__ Wt, float* __restrict__ Vt,
                            float* __restrict__ Ct) {
    int j = blockIdx.x;   // 256 blocks
    int k = threadIdx.x;  // 256 threads
    float a = W1[k * 512 + j];
    float b = W1[k * 512 + 256 + j];
    Wt[j * 256 + k] = a - b;
    Vt[j * 256 + k] = b;
    Ct[j * 256 + k] = W2[k * 512 + j] - W2[k * 512 + 256 + j];
}

// u = desc @ Wt (summing j), v = desc @ Vt. 8 rows of i per block.
// Also writes descriptors into out[:, 0:256].
__global__ void uv_kernel(const float* __restrict__ desc, const float* __restrict__ Wt,
                          const float* __restrict__ Vt, float* __restrict__ u,
                          float* __restrict__ v, float* __restrict__ out) {
    __shared__ float ds[8][256];
    int i0 = blockIdx.x * 8;  // 512 blocks
    int k = threadIdx.x;      // 256 threads
#pragma unroll
    for (int m = 0; m < 8; ++m) ds[m][k] = desc[(i0 + m) * 256 + k];
    __syncthreads();
    float au[8], av[8];
#pragma unroll
    for (int m = 0; m < 8; ++m) { au[m] = 0.f; av[m] = 0.f; }
    for (int j = 0; j < 256; ++j) {
        float wt = Wt[j * 256 + k];
        float vt = Vt[j * 256 + k];
#pragma unroll
        for (int m = 0; m < 8; ++m) {
            au[m] = fmaf(ds[m][j], wt, au[m]);
            av[m] = fmaf(ds[m][j], vt, av[m]);
        }
    }
#pragma unroll
    for (int m = 0; m < 8; ++m) {
        u[(i0 + m) * 256 + k] = au[m];
        v[(i0 + m) * 256 + k] = av[m];
        out[(i0 + m) * 512 + k] = ds[m][k];  // left half of concat
    }
}

// Per node i: build neighbor list (d2 <= R2, j != i) in LDS, then
// Mu[i,k] = sum_{j in list} u[j,k]; deg[i] = count.
__global__ void mask_mu_kernel(const float* __restrict__ centers, const float* __restrict__ u,
                               float* __restrict__ Mu, float* __restrict__ deg) {
    __shared__ int list[MAXDEG];
    __shared__ int cnt;
    int i = blockIdx.x;   // 4096 blocks
    int t = threadIdx.x;  // 256 threads
    if (t == 0) cnt = 0;
    __syncthreads();
    float cx = centers[3 * i], cy = centers[3 * i + 1], cz = centers[3 * i + 2];
    for (int j = t; j < NPTS; j += 256) {
        float dx = cx - centers[3 * j];
        float dy = cy - centers[3 * j + 1];
        float dz = cz - centers[3 * j + 2];
        float d2 = dx * dx + dy * dy + dz * dz;
        if (d2 <= R2 && j != i) {
            int p = atomicAdd(&cnt, 1);
            if (p < MAXDEG) list[p] = j;
        }
    }
    __syncthreads();
    int n = cnt < MAXDEG ? cnt : MAXDEG;
    float acc = 0.f;
    for (int idx = 0; idx < n; ++idx) {
        acc += u[list[idx] * 256 + t];
    }
    Mu[i * 256 + t] = acc;
    if (t == 0) deg[i] = (float)cnt;
}

// pooled = ((Mu + deg*(v+b1)) @ C + deg*b2) / n, written to out[:, 256:512].
__global__ void pooled_kernel(const float* __restrict__ Mu, const float* __restrict__ v,
                              const float* __restrict__ deg, const float* __restrict__ b1,
                              const float* __restrict__ b2, const float* __restrict__ Ct,
                              float* __restrict__ out) {
    __shared__ float T[8][256];
    __shared__ float dg[8];
    int i0 = blockIdx.x * 8;  // 512 blocks
    int k = threadIdx.x;      // 256 threads
    if (k < 8) dg[k] = deg[i0 + k];
    __syncthreads();
    float myb1 = b1[k];
#pragma unroll
    for (int m = 0; m < 8; ++m) {
        T[m][k] = Mu[(i0 + m) * 256 + k] + dg[m] * (v[(i0 + m) * 256 + k] + myb1);
    }
    __syncthreads();
    float acc[8];
#pragma unroll
    for (int m = 0; m < 8; ++m) acc[m] = 0.f;
    for (int j = 0; j < 256; ++j) {
        float c = Ct[j * 256 + k];
#pragma unroll
        for (int m = 0; m < 8; ++m) acc[m] = fmaf(T[m][j], c, acc[m]);
    }
    float myb2 = b2[k];
#pragma unroll
    for (int m = 0; m < 8; ++m) {
        out[(i0 + m) * 512 + 256 + k] = (acc[m] + dg[m] * myb2) * (1.0f / 4096.0f);
    }
}

extern "C" void kernel_launch(void* const* d_in, const int* in_sizes, int n_in,
                              void* d_out, int out_size, void* d_ws, size_t ws_size,
                              hipStream_t stream) {
    const float* centers = (const float*)d_in[0];  // 4096*3
    const float* desc    = (const float*)d_in[1];  // 4096*256
    const float* W1      = (const float*)d_in[2];  // 256*512
    const float* b1      = (const float*)d_in[3];  // 256
    const float* W2      = (const float*)d_in[4];  // 256*512
    const float* b2      = (const float*)d_in[5];  // 256
    float* out = (float*)d_out;                    // 4096*512

    float* ws = (float*)d_ws;
    float* u   = ws;                 // 4096*256
    float* v   = u + NPTS * DDIM;    // 4096*256
    float* Mu  = v + NPTS * DDIM;    // 4096*256
    float* deg = Mu + NPTS * DDIM;   // 4096
    float* Wt  = deg + NPTS;         // 256*256
    float* Vt  = Wt + DDIM * DDIM;   // 256*256
    float* Ct  = Vt + DDIM * DDIM;   // 256*256

    hipLaunchKernelGGL(prep_kernel, dim3(256), dim3(256), 0, stream, W1, W2, Wt, Vt, Ct);
    hipLaunchKernelGGL(uv_kernel, dim3(NPTS / 8), dim3(256), 0, stream, desc, Wt, Vt, u, v, out);
    hipLaunchKernelGGL(mask_mu_kernel, dim3(NPTS), dim3(256), 0, stream, centers, u, Mu, deg);
    hipLaunchKernelGGL(pooled_kernel, dim3(NPTS / 8), dim3(256), 0, stream, Mu, v, deg, b1, b2, Ct, out);
}

// Round 2
// 79.138 us; speedup vs baseline: 1.0145x; 1.0145x over previous
//
#include <hip/hip_runtime.h>

#define NPTS 4096
#define DDIM 256
#define R2 0.015625f
#define MAXDEG 512

// E[m,l] = sum_k (W1[k,m]-W1[k,m+256]) * C[k,l],  C[k,l] = W2[l,k]-W2[l,k+256]
// F[m,l] = sum_k  W1[k,m+256]          * C[k,l]
// g[l]   = sum_k  b1[k] * C[k,l]  +  b2[l]
// Stored E/F as [m][l] (row-major) so the hot GEMM reads them coalesced.
__global__ void prepEF_kernel(const float* __restrict__ W1, const float* __restrict__ W2,
                              const float* __restrict__ b1, const float* __restrict__ b2,
                              float* __restrict__ E, float* __restrict__ F,
                              float* __restrict__ g) {
    __shared__ float cs[256];
    __shared__ float b1s[256];
    int l = blockIdx.x;   // 256 blocks
    int m = threadIdx.x;  // 256 threads
    cs[m] = W2[l * 512 + m] - W2[l * 512 + 256 + m];
    b1s[m] = b1[m];
    __syncthreads();
    float ae = 0.f, af = 0.f, ag = 0.f;
#pragma unroll 4
    for (int k = 0; k < 256; ++k) {
        float w1a = W1[k * 512 + m];
        float w1b = W1[k * 512 + 256 + m];
        float c = cs[k];
        ae = fmaf(w1a - w1b, c, ae);
        af = fmaf(w1b, c, af);
        ag = fmaf(b1s[k], c, ag);
    }
    E[m * 256 + l] = ae;
    F[m * 256 + l] = af;
    if (m == 0) g[l] = ag + b2[l];
}

// P = desc @ E, Q = desc @ F; also writes desc into out[:, 0:256].
__global__ void gemmPQ_kernel(const float* __restrict__ desc, const float* __restrict__ E,
                              const float* __restrict__ F, float* __restrict__ P,
                              float* __restrict__ Q, float* __restrict__ out) {
    __shared__ float ds[8][256];
    int i0 = blockIdx.x * 8;  // 512 blocks
    int l = threadIdx.x;      // 256 threads
#pragma unroll
    for (int r = 0; r < 8; ++r) ds[r][l] = desc[(i0 + r) * 256 + l];
    __syncthreads();
    float ap[8], aq[8];
#pragma unroll
    for (int r = 0; r < 8; ++r) { ap[r] = 0.f; aq[r] = 0.f; }
#pragma unroll 4
    for (int m = 0; m < 256; ++m) {
        float e = E[m * 256 + l];
        float f = F[m * 256 + l];
#pragma unroll
        for (int r = 0; r < 8; ++r) {
            float d = ds[r][m];
            ap[r] = fmaf(d, e, ap[r]);
            aq[r] = fmaf(d, f, aq[r]);
        }
    }
#pragma unroll
    for (int r = 0; r < 8; ++r) {
        P[(i0 + r) * 256 + l] = ap[r];
        Q[(i0 + r) * 256 + l] = aq[r];
        out[(i0 + r) * 512 + l] = ds[r][l];
    }
}

// Per node i: neighbor list (d2<=R2, j!=i), then
// out[i, 256+t] = (sum_{j in N(i)} P[j,t] + deg_i*(Q[i,t]+g[t])) / n
__global__ void mask_out_kernel(const float* __restrict__ centers, const float* __restrict__ P,
                                const float* __restrict__ Q, const float* __restrict__ g,
                                float* __restrict__ out) {
    __shared__ int list[MAXDEG];
    __shared__ int cnt;
    int i = blockIdx.x;   // 4096 blocks
    int t = threadIdx.x;  // 256 threads
    if (t == 0) cnt = 0;
    __syncthreads();
    float cx = centers[3 * i], cy = centers[3 * i + 1], cz = centers[3 * i + 2];
    for (int j = t; j < NPTS; j += 256) {
        float dx = cx - centers[3 * j];
        float dy = cy - centers[3 * j + 1];
        float dz = cz - centers[3 * j + 2];
        float d2 = dx * dx + dy * dy + dz * dz;
        if (d2 <= R2 && j != i) {
            int p = atomicAdd(&cnt, 1);
            if (p < MAXDEG) list[p] = j;
        }
    }
    __syncthreads();
    int n = cnt < MAXDEG ? cnt : MAXDEG;
    float acc = 0.f;
    int idx = 0;
    // unroll-8 gather: break the ds_read -> global_load -> waitcnt chain
    for (; idx + 8 <= n; idx += 8) {
        int4 a = *(const int4*)&list[idx];
        int4 b = *(const int4*)&list[idx + 4];
        float s0 = P[a.x * 256 + t];
        float s1 = P[a.y * 256 + t];
        float s2 = P[a.z * 256 + t];
        float s3 = P[a.w * 256 + t];
        float s4 = P[b.x * 256 + t];
        float s5 = P[b.y * 256 + t];
        float s6 = P[b.z * 256 + t];
        float s7 = P[b.w * 256 + t];
        acc += ((s0 + s1) + (s2 + s3)) + ((s4 + s5) + (s6 + s7));
    }
    for (; idx < n; ++idx) acc += P[list[idx] * 256 + t];
    float dg = (float)cnt;
    out[i * 512 + 256 + t] = (acc + dg * (Q[i * 256 + t] + g[t])) * (1.0f / 4096.0f);
}

extern "C" void kernel_launch(void* const* d_in, const int* in_sizes, int n_in,
                              void* d_out, int out_size, void* d_ws, size_t ws_size,
                              hipStream_t stream) {
    const float* centers = (const float*)d_in[0];  // 4096*3
    const float* desc    = (const float*)d_in[1];  // 4096*256
    const float* W1      = (const float*)d_in[2];  // 256*512
    const float* b1      = (const float*)d_in[3];  // 256
    const float* W2      = (const float*)d_in[4];  // 256*512
    const float* b2      = (const float*)d_in[5];  // 256
    float* out = (float*)d_out;                    // 4096*512

    float* ws = (float*)d_ws;
    float* P = ws;                   // 4096*256
    float* Q = P + NPTS * DDIM;      // 4096*256
    float* E = Q + NPTS * DDIM;      // 256*256
    float* F = E + DDIM * DDIM;      // 256*256
    float* g = F + DDIM * DDIM;      // 256

    hipLaunchKernelGGL(prepEF_kernel, dim3(256), dim3(256), 0, stream, W1, W2, b1, b2, E, F, g);
    hipLaunchKernelGGL(gemmPQ_kernel, dim3(NPTS / 8), dim3(256), 0, stream, desc, E, F, P, Q, out);
    hipLaunchKernelGGL(mask_out_kernel, dim3(NPTS), dim3(256), 0, stream, centers, P, Q, g, out);
}

// Round 3
// 57.322 us; speedup vs baseline: 1.4005x; 1.3806x over previous
//
#include <hip/hip_runtime.h>

#define NPTS 4096
#define DDIM 256
#define R2V 0.015625f
#define MAXDEG 512

typedef __bf16 v8bf __attribute__((ext_vector_type(8)));
typedef float v4f __attribute__((ext_vector_type(4)));
typedef unsigned short ushort_t;

static __device__ __forceinline__ float bf2f(ushort_t s) {
    union { unsigned u; float f; } w; w.u = ((unsigned)s) << 16; return w.f;
}
static __device__ __forceinline__ ushort_t f2bf(float x) {
    return __builtin_bit_cast(ushort_t, (__bf16)x);
}

// Cast desc -> bf16 (db), and write desc f32 into out[:, 0:256].
__global__ void cast_kernel(const float* __restrict__ desc, ushort_t* __restrict__ db,
                            float* __restrict__ out) {
    int tid = blockIdx.x * 256 + threadIdx.x;  // 512 blocks
    int e = tid * 8;
    int i = e >> 8, c = e & 255;
    float4 f0 = *(const float4*)(desc + e);
    float4 f1 = *(const float4*)(desc + e + 4);
    ushort_t h[8];
    h[0] = f2bf(f0.x); h[1] = f2bf(f0.y); h[2] = f2bf(f0.z); h[3] = f2bf(f0.w);
    h[4] = f2bf(f1.x); h[5] = f2bf(f1.y); h[6] = f2bf(f1.z); h[7] = f2bf(f1.w);
    *(uint4*)(db + e) = *(uint4*)h;
    *(float4*)(out + i * 512 + c) = f0;
    *(float4*)(out + i * 512 + c + 4) = f1;
}

// EFt[l][m]     = E[m][l] = sum_k (W1[k,m]-W1[k,m+256]) * C[k,l]   (bf16, N x K layout)
// EFt[256+l][m] = F[m][l] = sum_k  W1[k,m+256]          * C[k,l]
// g[l] = sum_k b1[k]*C[k,l] + b2[l],  C[k,l] = W2[l,k] - W2[l,k+256]
__global__ void prepEFt_kernel(const float* __restrict__ W1, const float* __restrict__ W2,
                               const float* __restrict__ b1, const float* __restrict__ b2,
                               ushort_t* __restrict__ EFt, float* __restrict__ g) {
    __shared__ float cs[4][256];
    __shared__ float b1s[256];
    int l0 = blockIdx.x * 4;  // 64 blocks
    int m = threadIdx.x;      // 256 threads
    b1s[m] = b1[m];
#pragma unroll
    for (int q = 0; q < 4; ++q)
        cs[q][m] = W2[(l0 + q) * 512 + m] - W2[(l0 + q) * 512 + 256 + m];
    __syncthreads();
    float ae[4] = {0, 0, 0, 0}, af[4] = {0, 0, 0, 0}, ag[4] = {0, 0, 0, 0};
#pragma unroll 4
    for (int k = 0; k < 256; ++k) {
        float w1a = W1[k * 512 + m];
        float w1b = W1[k * 512 + 256 + m];
        float bk = b1s[k];
#pragma unroll
        for (int q = 0; q < 4; ++q) {
            float c = cs[q][k];
            ae[q] = fmaf(w1a - w1b, c, ae[q]);
            af[q] = fmaf(w1b, c, af[q]);
            ag[q] = fmaf(bk, c, ag[q]);
        }
    }
#pragma unroll
    for (int q = 0; q < 4; ++q) {
        EFt[(l0 + q) * 256 + m] = f2bf(ae[q]);
        EFt[(256 + l0 + q) * 256 + m] = f2bf(af[q]);
        if (m == 0) g[l0 + q] = ag[q] + b2[l0 + q];
    }
}

// PQ[i][l] (bf16, 4096x512) = desc_bf16 @ [E | F].  One-shot K=256 MFMA GEMM.
// BM=64, BN=128, 4 waves (2Mx2N), each wave 32x64 = 2x4 fragments of 16x16x32.
#define BM 64
#define BN 128
__launch_bounds__(256, 1)
__global__ void gemm_kernel(const ushort_t* __restrict__ db, const ushort_t* __restrict__ EFt,
                            ushort_t* __restrict__ PQ) {
    __shared__ ushort_t Asm[BM * 256];  // 32KB, 512B rows, XOR-swizzled
    __shared__ ushort_t Bsm[BN * 256];  // 64KB
    int tid = threadIdx.x;
    int i0 = blockIdx.x * BM;  // 64 M-blocks
    int n0 = blockIdx.y * BN;  // 4 N-blocks
    // stage A: 32KB = 8 x 16B chunks per thread, swizzle byte ^= (row&7)<<4
    const char* gA = (const char*)(db + i0 * 256);
#pragma unroll
    for (int c = 0; c < 8; ++c) {
        int f = (c * 256 + tid) * 16;
        int row = f >> 9, colb = f & 511;
        uint4 v = *(const uint4*)(gA + f);
        *(uint4*)((char*)Asm + row * 512 + (colb ^ ((row & 7) << 4))) = v;
    }
    // stage B: 64KB = 16 chunks per thread
    const char* gB = (const char*)(EFt + n0 * 256);
#pragma unroll
    for (int c = 0; c < 16; ++c) {
        int f = (c * 256 + tid) * 16;
        int row = f >> 9, colb = f & 511;
        uint4 v = *(const uint4*)(gB + f);
        *(uint4*)((char*)Bsm + row * 512 + (colb ^ ((row & 7) << 4))) = v;
    }
    __syncthreads();
    int w = tid >> 6, l = tid & 63;
    int mh = w >> 1, nh = w & 1;
    v4f acc[2][4] = {};
#pragma unroll
    for (int kk = 0; kk < 8; ++kk) {
        v8bf a[2], b[4];
        int kb = kk * 64 + ((l >> 4) * 16);  // byte offset of this lane's 8 bf16 k-run
#pragma unroll
        for (int mi = 0; mi < 2; ++mi) {
            int r = mh * 32 + mi * 16 + (l & 15);
            a[mi] = *(const v8bf*)((const char*)Asm + r * 512 + (kb ^ ((r & 7) << 4)));
        }
#pragma unroll
        for (int ni = 0; ni < 4; ++ni) {
            int r = nh * 64 + ni * 16 + (l & 15);
            b[ni] = *(const v8bf*)((const char*)Bsm + r * 512 + (kb ^ ((r & 7) << 4)));
        }
#pragma unroll
        for (int mi = 0; mi < 2; ++mi)
#pragma unroll
            for (int ni = 0; ni < 4; ++ni)
                acc[mi][ni] = __builtin_amdgcn_mfma_f32_16x16x32_bf16(a[mi], b[ni], acc[mi][ni], 0, 0, 0);
    }
    // epilogue: C/D layout col=lane&15, row=(lane>>4)*4+j
#pragma unroll
    for (int mi = 0; mi < 2; ++mi)
#pragma unroll
        for (int ni = 0; ni < 4; ++ni) {
            int rg = i0 + mh * 32 + mi * 16 + ((l >> 4) * 4);
            int cg = n0 + nh * 64 + ni * 16 + (l & 15);
#pragma unroll
            for (int j = 0; j < 4; ++j)
                PQ[(rg + j) * 512 + cg] = f2bf(acc[mi][ni][j]);
        }
}

// Per node i: neighbor list, then out[i,256+t] = (sum_j P[j,t] + deg*(Q[i,t]+g[t]))/4096
__global__ void mask_out_kernel(const float* __restrict__ centers, const ushort_t* __restrict__ PQ,
                                const float* __restrict__ g, float* __restrict__ out) {
    __shared__ int list[MAXDEG];
    __shared__ int cnt;
    int i = blockIdx.x;   // 4096 blocks
    int t = threadIdx.x;  // 256 threads
    if (t == 0) cnt = 0;
    __syncthreads();
    float cx = centers[3 * i], cy = centers[3 * i + 1], cz = centers[3 * i + 2];
    for (int j = t; j < NPTS; j += 256) {
        float dx = cx - centers[3 * j];
        float dy = cy - centers[3 * j + 1];
        float dz = cz - centers[3 * j + 2];
        float d2 = dx * dx + dy * dy + dz * dz;
        if (d2 <= R2V && j != i) {
            int p = atomicAdd(&cnt, 1);
            if (p < MAXDEG) list[p] = j;
        }
    }
    __syncthreads();
    int n = cnt < MAXDEG ? cnt : MAXDEG;
    float acc = 0.f;
    int idx = 0;
    for (; idx + 8 <= n; idx += 8) {
        int4 a = *(const int4*)&list[idx];
        int4 b = *(const int4*)&list[idx + 4];
        float s0 = bf2f(PQ[a.x * 512 + t]);
        float s1 = bf2f(PQ[a.y * 512 + t]);
        float s2 = bf2f(PQ[a.z * 512 + t]);
        float s3 = bf2f(PQ[a.w * 512 + t]);
        float s4 = bf2f(PQ[b.x * 512 + t]);
        float s5 = bf2f(PQ[b.y * 512 + t]);
        float s6 = bf2f(PQ[b.z * 512 + t]);
        float s7 = bf2f(PQ[b.w * 512 + t]);
        acc += ((s0 + s1) + (s2 + s3)) + ((s4 + s5) + (s6 + s7));
    }
    for (; idx < n; ++idx) acc += bf2f(PQ[list[idx] * 512 + t]);
    float dg = (float)cnt;
    out[i * 512 + 256 + t] = (acc + dg * (bf2f(PQ[i * 512 + 256 + t]) + g[t])) * (1.0f / 4096.0f);
}

extern "C" void kernel_launch(void* const* d_in, const int* in_sizes, int n_in,
                              void* d_out, int out_size, void* d_ws, size_t ws_size,
                              hipStream_t stream) {
    const float* centers = (const float*)d_in[0];
    const float* desc    = (const float*)d_in[1];
    const float* W1      = (const float*)d_in[2];
    const float* b1      = (const float*)d_in[3];
    const float* W2      = (const float*)d_in[4];
    const float* b2      = (const float*)d_in[5];
    float* out = (float*)d_out;

    char* ws = (char*)d_ws;
    ushort_t* db  = (ushort_t*)(ws);              // 4096*256*2B = 2MB
    ushort_t* EFt = (ushort_t*)(ws + 0x200000);   // 512*256*2B = 256KB
    ushort_t* PQ  = (ushort_t*)(ws + 0x240000);   // 4096*512*2B = 4MB
    float*    g   = (float*)(ws + 0x640000);      // 256*4B

    hipLaunchKernelGGL(cast_kernel, dim3(512), dim3(256), 0, stream, desc, db, out);
    hipLaunchKernelGGL(prepEFt_kernel, dim3(64), dim3(256), 0, stream, W1, W2, b1, b2, EFt, g);
    hipLaunchKernelGGL(gemm_kernel, dim3(64, 4), dim3(256), 0, stream, db, EFt, PQ);
    hipLaunchKernelGGL(mask_out_kernel, dim3(NPTS), dim3(256), 0, stream, centers, PQ, g, out);
}

// Round 4
// 49.062 us; speedup vs baseline: 1.6363x; 1.1684x over previous
//
#include <hip/hip_runtime.h>

#define NPTS 4096
#define DDIM 256
#define R2V 0.015625f
#define MAXDEG 512
#define NI 4

typedef __bf16 v8bf __attribute__((ext_vector_type(8)));
typedef float v4f __attribute__((ext_vector_type(4)));
typedef unsigned short ushort_t;

static __device__ __forceinline__ float bf2f(ushort_t s) {
    union { unsigned u; float f; } w; w.u = ((unsigned)s) << 16; return w.f;
}
static __device__ __forceinline__ ushort_t f2bf(float x) {
    return __builtin_bit_cast(ushort_t, (__bf16)x);
}

// EFt[l][m]     = E[m][l] = sum_k (W1[k,m]-W1[k,m+256]) * C[k,l]   (bf16, N x K layout)
// EFt[256+l][m] = F[m][l] = sum_k  W1[k,m+256]          * C[k,l]
// g[l] = sum_k b1[k]*C[k,l] + b2[l],  C[k,l] = W2[l,k] - W2[l,k+256]
__global__ void prepEFt_kernel(const float* __restrict__ W1, const float* __restrict__ W2,
                               const float* __restrict__ b1, const float* __restrict__ b2,
                               ushort_t* __restrict__ EFt, float* __restrict__ g) {
    __shared__ float cs[4][256];
    __shared__ float b1s[256];
    int l0 = blockIdx.x * 4;  // 64 blocks
    int m = threadIdx.x;      // 256 threads
    b1s[m] = b1[m];
#pragma unroll
    for (int q = 0; q < 4; ++q)
        cs[q][m] = W2[(l0 + q) * 512 + m] - W2[(l0 + q) * 512 + 256 + m];
    __syncthreads();
    float ae[4] = {0, 0, 0, 0}, af[4] = {0, 0, 0, 0}, ag[4] = {0, 0, 0, 0};
#pragma unroll 4
    for (int k = 0; k < 256; ++k) {
        float w1a = W1[k * 512 + m];
        float w1b = W1[k * 512 + 256 + m];
        float bk = b1s[k];
#pragma unroll
        for (int q = 0; q < 4; ++q) {
            float c = cs[q][k];
            ae[q] = fmaf(w1a - w1b, c, ae[q]);
            af[q] = fmaf(w1b, c, af[q]);
            ag[q] = fmaf(bk, c, ag[q]);
        }
    }
#pragma unroll
    for (int q = 0; q < 4; ++q) {
        EFt[(l0 + q) * 256 + m] = f2bf(ae[q]);
        EFt[(256 + l0 + q) * 256 + m] = f2bf(af[q]);
        if (m == 0) g[l0 + q] = ag[q] + b2[l0 + q];
    }
}

// PQ[i][l] (bf16, 4096x512) = bf16(desc) @ [E | F].  One-shot K=256 MFMA GEMM.
// BM=64, BN=128, 4 waves (2Mx2N), each wave 32x64 = 2x4 fragments of 16x16x32.
// A is staged straight from f32 desc, converted to bf16 in registers.
#define BM 64
#define BN 128
__launch_bounds__(256, 1)
__global__ void gemm_kernel(const float* __restrict__ desc, const ushort_t* __restrict__ EFt,
                            ushort_t* __restrict__ PQ) {
    __shared__ ushort_t Asm[BM * 256];  // 32KB, 512B rows, XOR-swizzled
    __shared__ ushort_t Bsm[BN * 256];  // 64KB
    int tid = threadIdx.x;
    int i0 = blockIdx.x * BM;  // 64 M-blocks
    int n0 = blockIdx.y * BN;  // 4 N-blocks
    // stage A: 2048 16B-bf16 chunks; each from 32B of f32
    const float* gA = desc + i0 * 256;
#pragma unroll
    for (int c = 0; c < 8; ++c) {
        int u = c * 256 + tid;
        int fb = u * 16;
        int row = fb >> 9, colb = fb & 511;
        float4 f0 = *(const float4*)(gA + u * 8);
        float4 f1 = *(const float4*)(gA + u * 8 + 4);
        ushort_t h[8];
        h[0] = f2bf(f0.x); h[1] = f2bf(f0.y); h[2] = f2bf(f0.z); h[3] = f2bf(f0.w);
        h[4] = f2bf(f1.x); h[5] = f2bf(f1.y); h[6] = f2bf(f1.z); h[7] = f2bf(f1.w);
        *(uint4*)((char*)Asm + row * 512 + (colb ^ ((row & 7) << 4))) = *(uint4*)h;
    }
    // stage B: 64KB = 16 chunks per thread (already bf16)
    const char* gB = (const char*)(EFt + n0 * 256);
#pragma unroll
    for (int c = 0; c < 16; ++c) {
        int f = (c * 256 + tid) * 16;
        int row = f >> 9, colb = f & 511;
        uint4 v = *(const uint4*)(gB + f);
        *(uint4*)((char*)Bsm + row * 512 + (colb ^ ((row & 7) << 4))) = v;
    }
    __syncthreads();
    int w = tid >> 6, l = tid & 63;
    int mh = w >> 1, nh = w & 1;
    v4f acc[2][4] = {};
#pragma unroll
    for (int kk = 0; kk < 8; ++kk) {
        v8bf a[2], b[4];
        int kb = kk * 64 + ((l >> 4) * 16);
#pragma unroll
        for (int mi = 0; mi < 2; ++mi) {
            int r = mh * 32 + mi * 16 + (l & 15);
            a[mi] = *(const v8bf*)((const char*)Asm + r * 512 + (kb ^ ((r & 7) << 4)));
        }
#pragma unroll
        for (int ni = 0; ni < 4; ++ni) {
            int r = nh * 64 + ni * 16 + (l & 15);
            b[ni] = *(const v8bf*)((const char*)Bsm + r * 512 + (kb ^ ((r & 7) << 4)));
        }
#pragma unroll
        for (int mi = 0; mi < 2; ++mi)
#pragma unroll
            for (int ni = 0; ni < 4; ++ni)
                acc[mi][ni] = __builtin_amdgcn_mfma_f32_16x16x32_bf16(a[mi], b[ni], acc[mi][ni], 0, 0, 0);
    }
#pragma unroll
    for (int mi = 0; mi < 2; ++mi)
#pragma unroll
        for (int ni = 0; ni < 4; ++ni) {
            int rg = i0 + mh * 32 + mi * 16 + ((l >> 4) * 4);
            int cg = n0 + nh * 64 + ni * 16 + (l & 15);
#pragma unroll
            for (int j = 0; j < 4; ++j)
                PQ[(rg + j) * 512 + cg] = f2bf(acc[mi][ni][j]);
        }
}

// NI=4 nodes per block. Distance phase: each j-load serves 4 checks.
// Then wave w gathers node i0+w (lane owns 4 columns, 8B loads),
// finalizes out[:,256:512], and copies desc row into out[:,0:256].
__global__ void mask_out_kernel(const float* __restrict__ centers, const ushort_t* __restrict__ PQ,
                                const float* __restrict__ g, const float* __restrict__ desc,
                                float* __restrict__ out) {
    __shared__ int list[NI][MAXDEG];
    __shared__ int cnt[NI];
    int i0 = blockIdx.x * NI;  // 1024 blocks
    int t = threadIdx.x;       // 256 threads
    if (t < NI) cnt[t] = 0;
    __syncthreads();
    float cx[NI], cy[NI], cz[NI];
#pragma unroll
    for (int q = 0; q < NI; ++q) {
        cx[q] = centers[3 * (i0 + q)];
        cy[q] = centers[3 * (i0 + q) + 1];
        cz[q] = centers[3 * (i0 + q) + 2];
    }
    for (int j = t; j < NPTS; j += 256) {
        float px = centers[3 * j], py = centers[3 * j + 1], pz = centers[3 * j + 2];
#pragma unroll
        for (int q = 0; q < NI; ++q) {
            float dx = cx[q] - px, dy = cy[q] - py, dz = cz[q] - pz;
            float d2 = dx * dx + dy * dy + dz * dz;
            if (d2 <= R2V && j != i0 + q) {
                int p = atomicAdd(&cnt[q], 1);
                if (p < MAXDEG) list[q][p] = j;
            }
        }
    }
    __syncthreads();
    int w = t >> 6, lane = t & 63;
    int i = i0 + w;
    int n = cnt[w] < MAXDEG ? cnt[w] : MAXDEG;
    int c0 = lane * 4;
    float a0 = 0.f, a1 = 0.f, a2 = 0.f, a3 = 0.f;
    int idx = 0;
    for (; idx + 4 <= n; idx += 4) {
        int4 jj = *(const int4*)&list[w][idx];
        ushort4 r0 = *(const ushort4*)(PQ + jj.x * 512 + c0);
        ushort4 r1 = *(const ushort4*)(PQ + jj.y * 512 + c0);
        ushort4 r2 = *(const ushort4*)(PQ + jj.z * 512 + c0);
        ushort4 r3 = *(const ushort4*)(PQ + jj.w * 512 + c0);
        a0 += (bf2f(r0.x) + bf2f(r1.x)) + (bf2f(r2.x) + bf2f(r3.x));
        a1 += (bf2f(r0.y) + bf2f(r1.y)) + (bf2f(r2.y) + bf2f(r3.y));
        a2 += (bf2f(r0.z) + bf2f(r1.z)) + (bf2f(r2.z) + bf2f(r3.z));
        a3 += (bf2f(r0.w) + bf2f(r1.w)) + (bf2f(r2.w) + bf2f(r3.w));
    }
    for (; idx < n; ++idx) {
        ushort4 r = *(const ushort4*)(PQ + list[w][idx] * 512 + c0);
        a0 += bf2f(r.x); a1 += bf2f(r.y); a2 += bf2f(r.z); a3 += bf2f(r.w);
    }
    float dg = (float)cnt[w];
    ushort4 qv = *(const ushort4*)(PQ + i * 512 + 256 + c0);
    float4 gv = *(const float4*)(g + c0);
    float4 o;
    o.x = (a0 + dg * (bf2f(qv.x) + gv.x)) * (1.0f / 4096.0f);
    o.y = (a1 + dg * (bf2f(qv.y) + gv.y)) * (1.0f / 4096.0f);
    o.z = (a2 + dg * (bf2f(qv.z) + gv.z)) * (1.0f / 4096.0f);
    o.w = (a3 + dg * (bf2f(qv.w) + gv.w)) * (1.0f / 4096.0f);
    *(float4*)(out + i * 512 + 256 + c0) = o;
    // concat left half: out[i, 0:256] = desc[i]
    *(float4*)(out + i * 512 + c0) = *(const float4*)(desc + i * 256 + c0);
}

extern "C" void kernel_launch(void* const* d_in, const int* in_sizes, int n_in,
                              void* d_out, int out_size, void* d_ws, size_t ws_size,
                              hipStream_t stream) {
    const float* centers = (const float*)d_in[0];
    const float* desc    = (const float*)d_in[1];
    const float* W1      = (const float*)d_in[2];
    const float* b1      = (const float*)d_in[3];
    const float* W2      = (const float*)d_in[4];
    const float* b2      = (const float*)d_in[5];
    float* out = (float*)d_out;

    char* ws = (char*)d_ws;
    ushort_t* EFt = (ushort_t*)(ws);              // 512*256*2B = 256KB
    ushort_t* PQ  = (ushort_t*)(ws + 0x40000);    // 4096*512*2B = 4MB
    float*    g   = (float*)(ws + 0x440000);      // 256*4B

    hipLaunchKernelGGL(prepEFt_kernel, dim3(64), dim3(256), 0, stream, W1, W2, b1, b2, EFt, g);
    hipLaunchKernelGGL(gemm_kernel, dim3(64, 4), dim3(256), 0, stream, desc, EFt, PQ);
    hipLaunchKernelGGL(mask_out_kernel, dim3(NPTS / NI), dim3(256), 0, stream, centers, PQ, g, desc, out);
}

// Round 5
// 42.157 us; speedup vs baseline: 1.9044x; 1.1638x over previous
//
#include <hip/hip_runtime.h>

#define NPTS 4096
#define DDIM 256
#define R2V 0.015625f
#define MAXDEG 512
#define NI 8

typedef __bf16 v8bf __attribute__((ext_vector_type(8)));
typedef float v4f __attribute__((ext_vector_type(4)));
typedef unsigned short ushort_t;

static __device__ __forceinline__ float bf2f(ushort_t s) {
    union { unsigned u; float f; } w; w.u = ((unsigned)s) << 16; return w.f;
}
static __device__ __forceinline__ ushort_t f2bf(float x) {
    return __builtin_bit_cast(ushort_t, (__bf16)x);
}

// EFt[l][m]     = E[m][l] = sum_k (W1[k,m]-W1[k,m+256]) * C[k,l]   (bf16, N x K layout)
// EFt[256+l][m] = F[m][l] = sum_k  W1[k,m+256]          * C[k,l]
// g[l] = sum_k b1[k]*C[k,l] + b2[l],  C[k,l] = W2[l,k] - W2[l,k+256]
// 256 blocks = (64 l-quads) x (4 m-quarters); in-block 4-way k-split + LDS reduce.
__global__ void prepEFt_kernel(const float* __restrict__ W1, const float* __restrict__ W2,
                               const float* __restrict__ b1, const float* __restrict__ b2,
                               ushort_t* __restrict__ EFt, float* __restrict__ g) {
    __shared__ float cs[4][256];     // C[k, l0+q], all k
    __shared__ float peA[4][4][64];  // [kq][q][ml]
    __shared__ float peB[4][4][64];
    __shared__ float pg[16];
    int b = blockIdx.x;          // 256 blocks
    int lq = b >> 2, mq = b & 3;
    int l0 = lq * 4;
    int t = threadIdx.x;         // 256 threads
    int kq = t >> 6, ml = t & 63;
    int m = mq * 64 + ml;
#pragma unroll
    for (int q = 0; q < 4; ++q)
        cs[q][t] = W2[(l0 + q) * 512 + t] - W2[(l0 + q) * 512 + 256 + t];
    __syncthreads();
    float ae[4] = {0, 0, 0, 0}, af[4] = {0, 0, 0, 0};
    int k0 = kq * 64;
#pragma unroll 4
    for (int kk = 0; kk < 64; ++kk) {
        int k = k0 + kk;
        float w1a = W1[k * 512 + m];
        float w1b = W1[k * 512 + 256 + m];
        float d = w1a - w1b;
#pragma unroll
        for (int q = 0; q < 4; ++q) {
            ae[q] = fmaf(d, cs[q][k], ae[q]);
            af[q] = fmaf(w1b, cs[q][k], af[q]);
        }
    }
#pragma unroll
    for (int q = 0; q < 4; ++q) { peA[kq][q][ml] = ae[q]; peB[kq][q][ml] = af[q]; }
    __syncthreads();
    // reduce: thread t -> (q2 = t>>6, ml2 = t&63)
    int q2 = t >> 6, ml2 = t & 63;
    float sE = (peA[0][q2][ml2] + peA[1][q2][ml2]) + (peA[2][q2][ml2] + peA[3][q2][ml2]);
    float sF = (peB[0][q2][ml2] + peB[1][q2][ml2]) + (peB[2][q2][ml2] + peB[3][q2][ml2]);
    EFt[(l0 + q2) * 256 + mq * 64 + ml2] = f2bf(sE);
    EFt[(256 + l0 + q2) * 256 + mq * 64 + ml2] = f2bf(sF);
    // g: only mq==0 blocks, 16 threads do 64-k partials, 4 threads finalize
    if (mq == 0) {
        if (t < 16) {
            int q = t >> 2, kqq = t & 3;
            float s = 0.f;
            for (int kk = 0; kk < 64; ++kk)
                s = fmaf(b1[kqq * 64 + kk], cs[q][kqq * 64 + kk], s);
            pg[t] = s;
        }
        __syncthreads();
        if (t < 4)
            g[l0 + t] = ((pg[t * 4] + pg[t * 4 + 1]) + (pg[t * 4 + 2] + pg[t * 4 + 3])) + b2[l0 + t];
    }
}

// PQ[i][l] (bf16, 4096x512) = bf16(desc) @ [E | F].  One-shot K=256 MFMA GEMM.
// BM=64, BN=128, 4 waves (2Mx2N), each wave 32x64 = 2x4 fragments of 16x16x32.
#define BM 64
#define BN 128
__launch_bounds__(256, 1)
__global__ void gemm_kernel(const float* __restrict__ desc, const ushort_t* __restrict__ EFt,
                            ushort_t* __restrict__ PQ) {
    __shared__ ushort_t Asm[BM * 256];  // 32KB, 512B rows, XOR-swizzled
    __shared__ ushort_t Bsm[BN * 256];  // 64KB
    int tid = threadIdx.x;
    int i0 = blockIdx.x * BM;  // 64 M-blocks
    int n0 = blockIdx.y * BN;  // 4 N-blocks
    const float* gA = desc + i0 * 256;
#pragma unroll
    for (int c = 0; c < 8; ++c) {
        int u = c * 256 + tid;
        int fb = u * 16;
        int row = fb >> 9, colb = fb & 511;
        float4 f0 = *(const float4*)(gA + u * 8);
        float4 f1 = *(const float4*)(gA + u * 8 + 4);
        ushort_t h[8];
        h[0] = f2bf(f0.x); h[1] = f2bf(f0.y); h[2] = f2bf(f0.z); h[3] = f2bf(f0.w);
        h[4] = f2bf(f1.x); h[5] = f2bf(f1.y); h[6] = f2bf(f1.z); h[7] = f2bf(f1.w);
        *(uint4*)((char*)Asm + row * 512 + (colb ^ ((row & 7) << 4))) = *(uint4*)h;
    }
    const char* gB = (const char*)(EFt + n0 * 256);
#pragma unroll
    for (int c = 0; c < 16; ++c) {
        int f = (c * 256 + tid) * 16;
        int row = f >> 9, colb = f & 511;
        uint4 v = *(const uint4*)(gB + f);
        *(uint4*)((char*)Bsm + row * 512 + (colb ^ ((row & 7) << 4))) = v;
    }
    __syncthreads();
    int w = tid >> 6, l = tid & 63;
    int mh = w >> 1, nh = w & 1;
    v4f acc[2][4] = {};
#pragma unroll
    for (int kk = 0; kk < 8; ++kk) {
        v8bf a[2], b[4];
        int kb = kk * 64 + ((l >> 4) * 16);
#pragma unroll
        for (int mi = 0; mi < 2; ++mi) {
            int r = mh * 32 + mi * 16 + (l & 15);
            a[mi] = *(const v8bf*)((const char*)Asm + r * 512 + (kb ^ ((r & 7) << 4)));
        }
#pragma unroll
        for (int ni = 0; ni < 4; ++ni) {
            int r = nh * 64 + ni * 16 + (l & 15);
            b[ni] = *(const v8bf*)((const char*)Bsm + r * 512 + (kb ^ ((r & 7) << 4)));
        }
#pragma unroll
        for (int mi = 0; mi < 2; ++mi)
#pragma unroll
            for (int ni = 0; ni < 4; ++ni)
                acc[mi][ni] = __builtin_amdgcn_mfma_f32_16x16x32_bf16(a[mi], b[ni], acc[mi][ni], 0, 0, 0);
    }
#pragma unroll
    for (int mi = 0; mi < 2; ++mi)
#pragma unroll
        for (int ni = 0; ni < 4; ++ni) {
            int rg = i0 + mh * 32 + mi * 16 + ((l >> 4) * 4);
            int cg = n0 + nh * 64 + ni * 16 + (l & 15);
#pragma unroll
            for (int j = 0; j < 4; ++j)
                PQ[(rg + j) * 512 + cg] = f2bf(acc[mi][ni][j]);
        }
}

// NI=8 nodes per block (512 blocks). Distance phase: each j-load serves 8 checks.
// Then wave w finalizes nodes 2w and 2w+1 (lane owns 4 columns, 8B gathers).
__global__ void mask_out_kernel(const float* __restrict__ centers, const ushort_t* __restrict__ PQ,
                                const float* __restrict__ g, const float* __restrict__ desc,
                                float* __restrict__ out) {
    __shared__ int list[NI][MAXDEG];
    __shared__ int cnt[NI];
    int i0 = blockIdx.x * NI;  // 512 blocks
    int t = threadIdx.x;       // 256 threads
    if (t < NI) cnt[t] = 0;
    __syncthreads();
    float cx[NI], cy[NI], cz[NI];
#pragma unroll
    for (int q = 0; q < NI; ++q) {
        cx[q] = centers[3 * (i0 + q)];
        cy[q] = centers[3 * (i0 + q) + 1];
        cz[q] = centers[3 * (i0 + q) + 2];
    }
    for (int j = t; j < NPTS; j += 256) {
        float px = centers[3 * j], py = centers[3 * j + 1], pz = centers[3 * j + 2];
#pragma unroll
        for (int q = 0; q < NI; ++q) {
            float dx = cx[q] - px, dy = cy[q] - py, dz = cz[q] - pz;
            float d2 = dx * dx + dy * dy + dz * dz;
            if (d2 <= R2V && j != i0 + q) {
                int p = atomicAdd(&cnt[q], 1);
                if (p < MAXDEG) list[q][p] = j;
            }
        }
    }
    __syncthreads();
    int w = t >> 6, lane = t & 63;
    int c0 = lane * 4;
#pragma unroll
    for (int s = 0; s < 2; ++s) {
        int q = w * 2 + s;
        int i = i0 + q;
        int n = cnt[q] < MAXDEG ? cnt[q] : MAXDEG;
        float a0 = 0.f, a1 = 0.f, a2 = 0.f, a3 = 0.f;
        int idx = 0;
        for (; idx + 4 <= n; idx += 4) {
            int4 jj = *(const int4*)&list[q][idx];
            ushort4 r0 = *(const ushort4*)(PQ + jj.x * 512 + c0);
            ushort4 r1 = *(const ushort4*)(PQ + jj.y * 512 + c0);
            ushort4 r2 = *(const ushort4*)(PQ + jj.z * 512 + c0);
            ushort4 r3 = *(const ushort4*)(PQ + jj.w * 512 + c0);
            a0 += (bf2f(r0.x) + bf2f(r1.x)) + (bf2f(r2.x) + bf2f(r3.x));
            a1 += (bf2f(r0.y) + bf2f(r1.y)) + (bf2f(r2.y) + bf2f(r3.y));
            a2 += (bf2f(r0.z) + bf2f(r1.z)) + (bf2f(r2.z) + bf2f(r3.z));
            a3 += (bf2f(r0.w) + bf2f(r1.w)) + (bf2f(r2.w) + bf2f(r3.w));
        }
        for (; idx < n; ++idx) {
            ushort4 r = *(const ushort4*)(PQ + list[q][idx] * 512 + c0);
            a0 += bf2f(r.x); a1 += bf2f(r.y); a2 += bf2f(r.z); a3 += bf2f(r.w);
        }
        float dg = (float)cnt[q];
        ushort4 qv = *(const ushort4*)(PQ + i * 512 + 256 + c0);
        float4 gv = *(const float4*)(g + c0);
        float4 o;
        o.x = (a0 + dg * (bf2f(qv.x) + gv.x)) * (1.0f / 4096.0f);
        o.y = (a1 + dg * (bf2f(qv.y) + gv.y)) * (1.0f / 4096.0f);
        o.z = (a2 + dg * (bf2f(qv.z) + gv.z)) * (1.0f / 4096.0f);
        o.w = (a3 + dg * (bf2f(qv.w) + gv.w)) * (1.0f / 4096.0f);
        *(float4*)(out + i * 512 + 256 + c0) = o;
        *(float4*)(out + i * 512 + c0) = *(const float4*)(desc + i * 256 + c0);
    }
}

extern "C" void kernel_launch(void* const* d_in, const int* in_sizes, int n_in,
                              void* d_out, int out_size, void* d_ws, size_t ws_size,
                              hipStream_t stream) {
    const float* centers = (const float*)d_in[0];
    const float* desc    = (const float*)d_in[1];
    const float* W1      = (const float*)d_in[2];
    const float* b1      = (const float*)d_in[3];
    const float* W2      = (const float*)d_in[4];
    const float* b2      = (const float*)d_in[5];
    float* out = (float*)d_out;

    char* ws = (char*)d_ws;
    ushort_t* EFt = (ushort_t*)(ws);              // 512*256*2B = 256KB
    ushort_t* PQ  = (ushort_t*)(ws + 0x40000);    // 4096*512*2B = 4MB
    float*    g   = (float*)(ws + 0x440000);      // 256*4B

    hipLaunchKernelGGL(prepEFt_kernel, dim3(256), dim3(256), 0, stream, W1, W2, b1, b2, EFt, g);
    hipLaunchKernelGGL(gemm_kernel, dim3(64, 4), dim3(256), 0, stream, desc, EFt, PQ);
    hipLaunchKernelGGL(mask_out_kernel, dim3(NPTS / NI), dim3(256), 0, stream, centers, PQ, g, desc, out);
}

// Round 6
// 42.103 us; speedup vs baseline: 1.9068x; 1.0013x over previous
//
#include <hip/hip_runtime.h>

#define NPTS 4096
#define DDIM 256
#define R2V 0.015625f
#define MAXDEG 512
#define NI 8

typedef __bf16 v8bf __attribute__((ext_vector_type(8)));
typedef float v4f __attribute__((ext_vector_type(4)));
typedef unsigned short ushort_t;

static __device__ __forceinline__ float bf2f(ushort_t s) {
    union { unsigned u; float f; } w; w.u = ((unsigned)s) << 16; return w.f;
}
static __device__ __forceinline__ ushort_t f2bf(float x) {
    return __builtin_bit_cast(ushort_t, (__bf16)x);
}

// EFt[l][m]     = E[m][l] = sum_k (W1[k,m]-W1[k,m+256]) * C[k,l]   (bf16, N x K layout)
// EFt[256+l][m] = F[m][l] = sum_k  W1[k,m+256]          * C[k,l]
// g[l] = sum_k b1[k]*C[k,l] + b2[l],  C[k,l] = W2[l,k] - W2[l,k+256]
// 256 blocks = (64 l-quads) x (4 m-quarters); in-block 4-way k-split + LDS reduce.
__global__ void prepEFt_kernel(const float* __restrict__ W1, const float* __restrict__ W2,
                               const float* __restrict__ b1, const float* __restrict__ b2,
                               ushort_t* __restrict__ EFt, float* __restrict__ g) {
    __shared__ float cs[4][256];     // C[k, l0+q], all k
    __shared__ float peA[4][4][64];  // [kq][q][ml]
    __shared__ float peB[4][4][64];
    __shared__ float pg[16];
    int b = blockIdx.x;          // 256 blocks
    int lq = b >> 2, mq = b & 3;
    int l0 = lq * 4;
    int t = threadIdx.x;         // 256 threads
    int kq = t >> 6, ml = t & 63;
    int m = mq * 64 + ml;
#pragma unroll
    for (int q = 0; q < 4; ++q)
        cs[q][t] = W2[(l0 + q) * 512 + t] - W2[(l0 + q) * 512 + 256 + t];
    __syncthreads();
    float ae[4] = {0, 0, 0, 0}, af[4] = {0, 0, 0, 0};
    int k0 = kq * 64;
#pragma unroll 4
    for (int kk = 0; kk < 64; ++kk) {
        int k = k0 + kk;
        float w1a = W1[k * 512 + m];
        float w1b = W1[k * 512 + 256 + m];
        float d = w1a - w1b;
#pragma unroll
        for (int q = 0; q < 4; ++q) {
            ae[q] = fmaf(d, cs[q][k], ae[q]);
            af[q] = fmaf(w1b, cs[q][k], af[q]);
        }
    }
#pragma unroll
    for (int q = 0; q < 4; ++q) { peA[kq][q][ml] = ae[q]; peB[kq][q][ml] = af[q]; }
    __syncthreads();
    int q2 = t >> 6, ml2 = t & 63;
    float sE = (peA[0][q2][ml2] + peA[1][q2][ml2]) + (peA[2][q2][ml2] + peA[3][q2][ml2]);
    float sF = (peB[0][q2][ml2] + peB[1][q2][ml2]) + (peB[2][q2][ml2] + peB[3][q2][ml2]);
    EFt[(l0 + q2) * 256 + mq * 64 + ml2] = f2bf(sE);
    EFt[(256 + l0 + q2) * 256 + mq * 64 + ml2] = f2bf(sF);
    if (mq == 0) {
        if (t < 16) {
            int q = t >> 2, kqq = t & 3;
            float s = 0.f;
            for (int kk = 0; kk < 64; ++kk)
                s = fmaf(b1[kqq * 64 + kk], cs[q][kqq * 64 + kk], s);
            pg[t] = s;
        }
        __syncthreads();
        if (t < 4)
            g[l0 + t] = ((pg[t * 4] + pg[t * 4 + 1]) + (pg[t * 4 + 2] + pg[t * 4 + 3])) + b2[l0 + t];
    }
}

// PQ[i][l] (bf16, 4096x512) = bf16(desc) @ [E | F].  One-shot K=256 MFMA GEMM.
// BM=64, BN=128, 4 waves (2Mx2N), each wave 32x64 = 2x4 fragments of 16x16x32.
// blockIdx.y==0 blocks also write out[i, 0:256] = desc[i] (they hold the f32 regs).
#define BM 64
#define BN 128
__launch_bounds__(256, 1)
__global__ void gemm_kernel(const float* __restrict__ desc, const ushort_t* __restrict__ EFt,
                            ushort_t* __restrict__ PQ, float* __restrict__ out) {
    __shared__ ushort_t Asm[BM * 256];  // 32KB, 512B rows, XOR-swizzled
    __shared__ ushort_t Bsm[BN * 256];  // 64KB
    int tid = threadIdx.x;
    int i0 = blockIdx.x * BM;  // 64 M-blocks
    int n0 = blockIdx.y * BN;  // 4 N-blocks
    const float* gA = desc + i0 * 256;
#pragma unroll
    for (int c = 0; c < 8; ++c) {
        int u = c * 256 + tid;
        int fb = u * 16;
        int row = fb >> 9, colb = fb & 511;
        float4 f0 = *(const float4*)(gA + u * 8);
        float4 f1 = *(const float4*)(gA + u * 8 + 4);
        ushort_t h[8];
        h[0] = f2bf(f0.x); h[1] = f2bf(f0.y); h[2] = f2bf(f0.z); h[3] = f2bf(f0.w);
        h[4] = f2bf(f1.x); h[5] = f2bf(f1.y); h[6] = f2bf(f1.z); h[7] = f2bf(f1.w);
        *(uint4*)((char*)Asm + row * 512 + (colb ^ ((row & 7) << 4))) = *(uint4*)h;
        if (blockIdx.y == 0) {
            int col = (u & 31) * 8;  // column within the 256-wide desc row
            *(float4*)(out + (i0 + row) * 512 + col) = f0;
            *(float4*)(out + (i0 + row) * 512 + col + 4) = f1;
        }
    }
    const char* gB = (const char*)(EFt + n0 * 256);
#pragma unroll
    for (int c = 0; c < 16; ++c) {
        int f = (c * 256 + tid) * 16;
        int row = f >> 9, colb = f & 511;
        uint4 v = *(const uint4*)(gB + f);
        *(uint4*)((char*)Bsm + row * 512 + (colb ^ ((row & 7) << 4))) = v;
    }
    __syncthreads();
    int w = tid >> 6, l = tid & 63;
    int mh = w >> 1, nh = w & 1;
    v4f acc[2][4] = {};
#pragma unroll
    for (int kk = 0; kk < 8; ++kk) {
        v8bf a[2], b[4];
        int kb = kk * 64 + ((l >> 4) * 16);
#pragma unroll
        for (int mi = 0; mi < 2; ++mi) {
            int r = mh * 32 + mi * 16 + (l & 15);
            a[mi] = *(const v8bf*)((const char*)Asm + r * 512 + (kb ^ ((r & 7) << 4)));
        }
#pragma unroll
        for (int ni = 0; ni < 4; ++ni) {
            int r = nh * 64 + ni * 16 + (l & 15);
            b[ni] = *(const v8bf*)((const char*)Bsm + r * 512 + (kb ^ ((r & 7) << 4)));
        }
#pragma unroll
        for (int mi = 0; mi < 2; ++mi)
#pragma unroll
            for (int ni = 0; ni < 4; ++ni)
                acc[mi][ni] = __builtin_amdgcn_mfma_f32_16x16x32_bf16(a[mi], b[ni], acc[mi][ni], 0, 0, 0);
    }
#pragma unroll
    for (int mi = 0; mi < 2; ++mi)
#pragma unroll
        for (int ni = 0; ni < 4; ++ni) {
            int rg = i0 + mh * 32 + mi * 16 + ((l >> 4) * 4);
            int cg = n0 + nh * 64 + ni * 16 + (l & 15);
#pragma unroll
            for (int j = 0; j < 4; ++j)
                PQ[(rg + j) * 512 + cg] = f2bf(acc[mi][ni][j]);
        }
}

// NI=8 nodes per block (512 blocks). Dot-form distance test:
// d2 <= R2  <=>  2*(ci.pj) - |pj|^2 >= |ci|^2 - R2.  |pj|^2 amortized over 8 nodes.
__global__ void mask_out_kernel(const float* __restrict__ centers, const ushort_t* __restrict__ PQ,
                                const float* __restrict__ g, float* __restrict__ out) {
    __shared__ int list[NI][MAXDEG];
    __shared__ int cnt[NI];
    int i0 = blockIdx.x * NI;  // 512 blocks
    int t = threadIdx.x;       // 256 threads
    if (t < NI) cnt[t] = 0;
    __syncthreads();
    float cx[NI], cy[NI], cz[NI], aq[NI];
#pragma unroll
    for (int q = 0; q < NI; ++q) {
        cx[q] = centers[3 * (i0 + q)];
        cy[q] = centers[3 * (i0 + q) + 1];
        cz[q] = centers[3 * (i0 + q) + 2];
        aq[q] = fmaf(cx[q], cx[q], fmaf(cy[q], cy[q], cz[q] * cz[q])) - R2V;
    }
    for (int j = t; j < NPTS; j += 256) {
        float px = centers[3 * j], py = centers[3 * j + 1], pz = centers[3 * j + 2];
        float nj = fmaf(px, px, fmaf(py, py, pz * pz));
#pragma unroll
        for (int q = 0; q < NI; ++q) {
            float s = fmaf(cx[q], px, fmaf(cy[q], py, cz[q] * pz));
            if (fmaf(2.0f, s, -nj) >= aq[q] && j != i0 + q) {
                int p = atomicAdd(&cnt[q], 1);
                if (p < MAXDEG) list[q][p] = j;
            }
        }
    }
    __syncthreads();
    int w = t >> 6, lane = t & 63;
    int c0 = lane * 4;
#pragma unroll
    for (int s = 0; s < 2; ++s) {
        int q = w * 2 + s;
        int i = i0 + q;
        int n = cnt[q] < MAXDEG ? cnt[q] : MAXDEG;
        float a0 = 0.f, a1 = 0.f, a2 = 0.f, a3 = 0.f;
        int idx = 0;
        for (; idx + 4 <= n; idx += 4) {
            int4 jj = *(const int4*)&list[q][idx];
            ushort4 r0 = *(const ushort4*)(PQ + jj.x * 512 + c0);
            ushort4 r1 = *(const ushort4*)(PQ + jj.y * 512 + c0);
            ushort4 r2 = *(const ushort4*)(PQ + jj.z * 512 + c0);
            ushort4 r3 = *(const ushort4*)(PQ + jj.w * 512 + c0);
            a0 += (bf2f(r0.x) + bf2f(r1.x)) + (bf2f(r2.x) + bf2f(r3.x));
            a1 += (bf2f(r0.y) + bf2f(r1.y)) + (bf2f(r2.y) + bf2f(r3.y));
            a2 += (bf2f(r0.z) + bf2f(r1.z)) + (bf2f(r2.z) + bf2f(r3.z));
            a3 += (bf2f(r0.w) + bf2f(r1.w)) + (bf2f(r2.w) + bf2f(r3.w));
        }
        for (; idx < n; ++idx) {
            ushort4 r = *(const ushort4*)(PQ + list[q][idx] * 512 + c0);
            a0 += bf2f(r.x); a1 += bf2f(r.y); a2 += bf2f(r.z); a3 += bf2f(r.w);
        }
        float dg = (float)cnt[q];
        ushort4 qv = *(const ushort4*)(PQ + i * 512 + 256 + c0);
        float4 gv = *(const float4*)(g + c0);
        float4 o;
        o.x = (a0 + dg * (bf2f(qv.x) + gv.x)) * (1.0f / 4096.0f);
        o.y = (a1 + dg * (bf2f(qv.y) + gv.y)) * (1.0f / 4096.0f);
        o.z = (a2 + dg * (bf2f(qv.z) + gv.z)) * (1.0f / 4096.0f);
        o.w = (a3 + dg * (bf2f(qv.w) + gv.w)) * (1.0f / 4096.0f);
        *(float4*)(out + i * 512 + 256 + c0) = o;
    }
}

extern "C" void kernel_launch(void* const* d_in, const int* in_sizes, int n_in,
                              void* d_out, int out_size, void* d_ws, size_t ws_size,
                              hipStream_t stream) {
    const float* centers = (const float*)d_in[0];
    const float* desc    = (const float*)d_in[1];
    const float* W1      = (const float*)d_in[2];
    const float* b1      = (const float*)d_in[3];
    const float* W2      = (const float*)d_in[4];
    const float* b2      = (const float*)d_in[5];
    float* out = (float*)d_out;

    char* ws = (char*)d_ws;
    ushort_t* EFt = (ushort_t*)(ws);              // 512*256*2B = 256KB
    ushort_t* PQ  = (ushort_t*)(ws + 0x40000);    // 4096*512*2B = 4MB
    float*    g   = (float*)(ws + 0x440000);      // 256*4B

    hipLaunchKernelGGL(prepEFt_kernel, dim3(256), dim3(256), 0, stream, W1, W2, b1, b2, EFt, g);
    hipLaunchKernelGGL(gemm_kernel, dim3(64, 4), dim3(256), 0, stream, desc, EFt, PQ, out);
    hipLaunchKernelGGL(mask_out_kernel, dim3(NPTS / NI), dim3(256), 0, stream, centers, PQ, g, out);
}